// Round 4
// baseline (462.286 us; speedup 1.0000x reference)
//
#include <hip/hip_runtime.h>
#include <math.h>

// Caps1D dynamic routing.
// u: [B=1024, R=2336, M=4] fp32 ; W: [K=2, R=2336, M=4, P=16] fp32
// out: classes [B, K] fp32 = norm/(1+norm) of final squash input.
//
// One block per (b,k). u_ji register-resident: 1024 threads x 3 rows.
//
// REGISTER-CAP LESSON (rounds 1-3): hipcc's __launch_bounds__ 2nd-arg
// translation floors the occupancy target at ~2 blocks/CU, so any
// 1024-thread block gets a 64-VGPR cap no matter what ((1024,1) and
// (1024,4) both measured VGPR_Count=64 -> ~50 spilled floats/thread ->
// 670 MB scratch traffic, 455us). Fix: native clang attributes.
// amdgpu_waves_per_eu(4,4) pins the allocator at 4 waves/EU -> 512/4 =
// 128-VGPR budget, which this body (uji=48 + ~60 working) fits spill-free.

#define THREADS 1024
#define ROWS 3            // ceil(2336 / 1024)
#define NWAVE (THREADS / 64)

__global__
__attribute__((amdgpu_flat_work_group_size(1024, 1024)))
__attribute__((amdgpu_waves_per_eu(4, 4)))
void caps_routing_kernel(const float* __restrict__ u,
                         const float* __restrict__ W,
                         float* __restrict__ out)
{
    constexpr int K = 2, R = 2336, P = 16;

    const int bi   = blockIdx.x;
    const int b    = bi >> 1;
    const int k    = bi & 1;
    const int tid  = threadIdx.x;
    const int lane = tid & 63;
    const int wave = tid >> 6;

    __shared__ float redmax[NWAVE];
    __shared__ float red[NWAVE][17];   // 16 s-partials + sumexp per wave
    __shared__ float vbuf[P];

    const float4* __restrict__ u4 = (const float4*)u;
    const float4* __restrict__ w4 = (const float4*)W;

    float uji[ROWS][P];
    float brow[ROWS];

    // rows 0,1 always valid (tid+1024 < 2336); row 2 valid iff tid < 288
    const bool v2 = (tid + 2 * THREADS) < R;

    // ---- build u_ji = u[b,r,:] @ W[k,r,:,:]  (M=4 contraction) ----
    // One row at a time: <=16 W float4 loads in flight while only the
    // earlier rows' uji (<=32 floats) are live.
    #pragma unroll
    for (int j = 0; j < ROWS; ++j) {
        const int r = tid + j * THREADS;
        const bool valid = (j < 2) | v2;
        brow[j] = valid ? 0.0f : -INFINITY;
        if (valid) {
            float4 uu = u4[b * R + r];                 // u[b,r,0..3]
            const float4* wp = w4 + (size_t)(k * R + r) * 16;
            // m = 0 (init), then m = 1..3 (fma)
            {
                float4 w0 = wp[0], w1 = wp[1], w2 = wp[2], w3 = wp[3];
                uji[j][ 0] = uu.x * w0.x; uji[j][ 1] = uu.x * w0.y;
                uji[j][ 2] = uu.x * w0.z; uji[j][ 3] = uu.x * w0.w;
                uji[j][ 4] = uu.x * w1.x; uji[j][ 5] = uu.x * w1.y;
                uji[j][ 6] = uu.x * w1.z; uji[j][ 7] = uu.x * w1.w;
                uji[j][ 8] = uu.x * w2.x; uji[j][ 9] = uu.x * w2.y;
                uji[j][10] = uu.x * w2.z; uji[j][11] = uu.x * w2.w;
                uji[j][12] = uu.x * w3.x; uji[j][13] = uu.x * w3.y;
                uji[j][14] = uu.x * w3.z; uji[j][15] = uu.x * w3.w;
            }
            #pragma unroll
            for (int m = 1; m < 4; ++m) {
                float um = (m == 1) ? uu.y : (m == 2) ? uu.z : uu.w;
                float4 w0 = wp[4*m+0], w1 = wp[4*m+1], w2 = wp[4*m+2], w3 = wp[4*m+3];
                uji[j][ 0] += um * w0.x; uji[j][ 1] += um * w0.y;
                uji[j][ 2] += um * w0.z; uji[j][ 3] += um * w0.w;
                uji[j][ 4] += um * w1.x; uji[j][ 5] += um * w1.y;
                uji[j][ 6] += um * w1.z; uji[j][ 7] += um * w1.w;
                uji[j][ 8] += um * w2.x; uji[j][ 9] += um * w2.y;
                uji[j][10] += um * w2.z; uji[j][11] += um * w2.w;
                uji[j][12] += um * w3.x; uji[j][13] += um * w3.y;
                uji[j][14] += um * w3.z; uji[j][15] += um * w3.w;
            }
        } else {
            #pragma unroll
            for (int p = 0; p < P; ++p) uji[j][p] = 0.0f;
        }
    }

    // ---- 3 routing iterations ----
    for (int it = 0; it < 3; ++it) {
        float e[ROWS];
        if (it == 0) {
            // b == 0: softmax is uniform; e_r = 1 for valid rows
            e[0] = 1.0f; e[1] = 1.0f; e[2] = v2 ? 1.0f : 0.0f;
        } else {
            // block max of logits (softmax stability)
            float mloc = fmaxf(fmaxf(brow[0], brow[1]), brow[2]);
            #pragma unroll
            for (int o = 32; o > 0; o >>= 1) mloc = fmaxf(mloc, __shfl_down(mloc, o));
            if (lane == 0) redmax[wave] = mloc;
            __syncthreads();
            float bmax = redmax[0];
            #pragma unroll
            for (int w = 1; w < NWAVE; ++w) bmax = fmaxf(bmax, redmax[w]);
            #pragma unroll
            for (int j = 0; j < ROWS; ++j) e[j] = __expf(brow[j] - bmax); // -inf -> 0
        }

        // fused weighted sums: s_p = sum_r e_r * uji[r,p], se = sum_r e_r
        float sloc[P];
        #pragma unroll
        for (int p = 0; p < P; ++p)
            sloc[p] = e[0] * uji[0][p] + e[1] * uji[1][p] + e[2] * uji[2][p];
        float seloc = e[0] + e[1] + e[2];
        #pragma unroll
        for (int o = 32; o > 0; o >>= 1) {
            seloc += __shfl_down(seloc, o);
            #pragma unroll
            for (int p = 0; p < P; ++p) sloc[p] += __shfl_down(sloc[p], o);
        }
        if (lane == 0) {
            #pragma unroll
            for (int p = 0; p < P; ++p) red[wave][p] = sloc[p];
            red[wave][16] = seloc;
        }
        __syncthreads();

        // wave 0, lanes 0..16: column sums; lanes 0..15 finish squash in parallel
        if (wave == 0 && lane < 17) {
            float col = red[0][lane];
            #pragma unroll
            for (int w = 1; w < NWAVE; ++w) col += red[w][lane];
            // norm_raw = sum_p col_p^2 over lanes 0..15 (xor net stays in [0,16))
            float nr = col * col;
            nr += __shfl_xor(nr, 1);
            nr += __shfl_xor(nr, 2);
            nr += __shfl_xor(nr, 4);
            nr += __shfl_xor(nr, 8);
            float se = __shfl(col, 16);          // lane 16 holds sum of e
            float inv_se = 1.0f / se;
            float norm = nr * inv_se * inv_se;   // |s|^2 of weighted mean
            if (lane < 16) {
                // v = s * sqrt(norm)/(1+norm), with s = col/se
                float f = sqrtf(norm) / (1.0f + norm);
                vbuf[lane] = col * inv_se * f;
                if (it == 2 && lane == 0) out[b * K + k] = norm / (1.0f + norm);
            }
        }
        __syncthreads();

        // logit update: b_r += dot(u_ji[r,:], v)   (skipped on last iter)
        if (it < 2) {
            float v[P];
            #pragma unroll
            for (int p = 0; p < P; ++p) v[p] = vbuf[p];
            #pragma unroll
            for (int j = 0; j < ROWS; ++j) {
                float d = 0.0f;
                #pragma unroll
                for (int p = 0; p < P; ++p) d += uji[j][p] * v[p];
                brow[j] += d;
            }
        }
    }
}

extern "C" void kernel_launch(void* const* d_in, const int* in_sizes, int n_in,
                              void* d_out, int out_size, void* d_ws, size_t ws_size,
                              hipStream_t stream) {
    const float* u = (const float*)d_in[0];   // [1024, 2336, 4]
    const float* W = (const float*)d_in[1];   // [2, 2336, 4, 16]
    float* out = (float*)d_out;               // [1024, 2]
    caps_routing_kernel<<<dim3(2048), dim3(THREADS), 0, stream>>>(u, W, out);
}

// Round 5
// 368.125 us; speedup vs baseline: 1.2558x; 1.2558x over previous
//
#include <hip/hip_runtime.h>
#include <math.h>

// Caps1D dynamic routing.
// u: [B=1024, R=2336, M=4] fp32 ; W: [K=2, R=2336, M=4, P=16] fp32
// out: classes [B, K] fp32 = norm/(1+norm) of final squash input.
//
// One block per (b,k); u_ji register-resident (512 thr x 5 rows x 16 = 80 VGPR).
//
// REGISTER-CAP LESSONS (rounds 1-4, measured):
//   (512,2)            -> VGPR 128   (the only config that gave 128)
//   (1024,{1,4}), amdgpu_waves_per_eu(4,4) -> VGPR 64 ALWAYS for 1024-thr WGs
// So: 512 threads, launch_bounds(512,2), and keep peak live pressure < 128:
//   - cumulative-V trick: b_r == dot(u_ji[r], sum of past v) -> no persistent
//     brow[]/v[]; logits recomputed from vbuf (LDS) each iteration.
//   - 17-wide shuffle reduction split into 9+8 chunks.

#define THREADS 512
#define ROWS 5            // ceil(2336 / 512)
#define NWAVE (THREADS / 64)

__global__ __launch_bounds__(THREADS, 2)
void caps_routing_kernel(const float* __restrict__ u,
                         const float* __restrict__ W,
                         float* __restrict__ out)
{
    constexpr int K = 2, R = 2336, P = 16;

    // XCD swizzle: siblings (b,k=0) and (b,k=1) are 8 blocks apart -> same XCD
    // under round-robin dispatch -> u[b] L2 fetch shared between them.
    const int bi   = blockIdx.x;
    const int k    = (bi >> 3) & 1;
    const int b    = (bi & 7) | ((bi >> 4) << 3);
    const int tid  = threadIdx.x;
    const int lane = tid & 63;
    const int wave = tid >> 6;

    __shared__ float redmax[NWAVE];
    __shared__ float red[NWAVE][17];   // 16 s-partials + sumexp per wave
    __shared__ float vbuf[P];          // CUMULATIVE v (sum of v over iters)

    const float4* __restrict__ u4 = (const float4*)u;
    const float4* __restrict__ w4 = (const float4*)W;

    float uji[ROWS][P];
    // rows 0..3 always valid (tid+3*512 = tid+1536 < 2336); row 4 iff tid < 288
    const bool v4 = (tid + 4 * THREADS) < R;

    // ---- build u_ji = u[b,r,:] @ W[k,r,:,:]  (M=4 contraction) ----
    #pragma unroll
    for (int j = 0; j < ROWS; ++j) {
        const int r = tid + j * THREADS;
        const bool valid = (j < 4) | v4;
        if (valid) {
            float4 uu = u4[b * R + r];
            const float4* wp = w4 + (size_t)(k * R + r) * 16;
            {
                float4 w0 = wp[0], w1 = wp[1], w2 = wp[2], w3 = wp[3];
                uji[j][ 0] = uu.x * w0.x; uji[j][ 1] = uu.x * w0.y;
                uji[j][ 2] = uu.x * w0.z; uji[j][ 3] = uu.x * w0.w;
                uji[j][ 4] = uu.x * w1.x; uji[j][ 5] = uu.x * w1.y;
                uji[j][ 6] = uu.x * w1.z; uji[j][ 7] = uu.x * w1.w;
                uji[j][ 8] = uu.x * w2.x; uji[j][ 9] = uu.x * w2.y;
                uji[j][10] = uu.x * w2.z; uji[j][11] = uu.x * w2.w;
                uji[j][12] = uu.x * w3.x; uji[j][13] = uu.x * w3.y;
                uji[j][14] = uu.x * w3.z; uji[j][15] = uu.x * w3.w;
            }
            #pragma unroll
            for (int m = 1; m < 4; ++m) {
                float um = (m == 1) ? uu.y : (m == 2) ? uu.z : uu.w;
                float4 w0 = wp[4*m+0], w1 = wp[4*m+1], w2 = wp[4*m+2], w3 = wp[4*m+3];
                uji[j][ 0] += um * w0.x; uji[j][ 1] += um * w0.y;
                uji[j][ 2] += um * w0.z; uji[j][ 3] += um * w0.w;
                uji[j][ 4] += um * w1.x; uji[j][ 5] += um * w1.y;
                uji[j][ 6] += um * w1.z; uji[j][ 7] += um * w1.w;
                uji[j][ 8] += um * w2.x; uji[j][ 9] += um * w2.y;
                uji[j][10] += um * w2.z; uji[j][11] += um * w2.w;
                uji[j][12] += um * w3.x; uji[j][13] += um * w3.y;
                uji[j][14] += um * w3.z; uji[j][15] += um * w3.w;
            }
        } else {
            #pragma unroll
            for (int p = 0; p < P; ++p) uji[j][p] = 0.0f;
        }
    }

    // ---- 3 routing iterations (cumulative-V form) ----
    for (int it = 0; it < 3; ++it) {
        float e[ROWS];                 // logits, then exp weights
        if (it == 0) {
            // b == 0: uniform softmax
            e[0] = 1.0f; e[1] = 1.0f; e[2] = 1.0f; e[3] = 1.0f;
            e[4] = v4 ? 1.0f : 0.0f;
        } else {
            // logits: b_r = dot(u_ji[r], Vcum)   (Vcum in vbuf)
            float mloc = -INFINITY;
            #pragma unroll
            for (int j = 0; j < ROWS; ++j) {
                float d = 0.0f;
                #pragma unroll
                for (int p = 0; p < P; ++p) d += uji[j][p] * vbuf[p];
                e[j] = ((j < 4) | v4) ? d : -INFINITY;
                mloc = fmaxf(mloc, e[j]);
            }
            #pragma unroll
            for (int o = 32; o > 0; o >>= 1) mloc = fmaxf(mloc, __shfl_down(mloc, o));
            if (lane == 0) redmax[wave] = mloc;
            __syncthreads();
            float bmax = redmax[0];
            #pragma unroll
            for (int w = 1; w < NWAVE; ++w) bmax = fmaxf(bmax, redmax[w]);
            #pragma unroll
            for (int j = 0; j < ROWS; ++j) e[j] = __expf(e[j] - bmax); // -inf -> 0
        }

        // weighted sums s_p = sum_r e_r*uji[r,p], se = sum_r e_r — in 2 chunks
        {   // chunk A: p = 0..7 plus se (9 values)
            float ch[9];
            #pragma unroll
            for (int p = 0; p < 8; ++p)
                ch[p] = e[0]*uji[0][p] + e[1]*uji[1][p] + e[2]*uji[2][p]
                      + e[3]*uji[3][p] + e[4]*uji[4][p];
            ch[8] = e[0] + e[1] + e[2] + e[3] + e[4];
            #pragma unroll
            for (int o = 32; o > 0; o >>= 1) {
                #pragma unroll
                for (int q = 0; q < 9; ++q) ch[q] += __shfl_down(ch[q], o);
            }
            if (lane == 0) {
                #pragma unroll
                for (int q = 0; q < 8; ++q) red[wave][q] = ch[q];
                red[wave][16] = ch[8];
            }
        }
        {   // chunk B: p = 8..15
            float ch[8];
            #pragma unroll
            for (int p = 0; p < 8; ++p)
                ch[p] = e[0]*uji[0][8+p] + e[1]*uji[1][8+p] + e[2]*uji[2][8+p]
                      + e[3]*uji[3][8+p] + e[4]*uji[4][8+p];
            #pragma unroll
            for (int o = 32; o > 0; o >>= 1) {
                #pragma unroll
                for (int q = 0; q < 8; ++q) ch[q] += __shfl_down(ch[q], o);
            }
            if (lane == 0) {
                #pragma unroll
                for (int q = 0; q < 8; ++q) red[wave][8 + q] = ch[q];
            }
        }
        __syncthreads();

        // wave 0, lanes 0..16: cross-wave column sums + squash
        if (wave == 0 && lane < 17) {
            float col = red[0][lane];
            #pragma unroll
            for (int w = 1; w < NWAVE; ++w) col += red[w][lane];
            float nr = col * col;                    // lanes 0..15: s-partials
            nr += __shfl_xor(nr, 1);
            nr += __shfl_xor(nr, 2);
            nr += __shfl_xor(nr, 4);
            nr += __shfl_xor(nr, 8);
            float se = __shfl(col, 16);              // lane 16 holds sum of e
            float inv_se = 1.0f / se;
            float norm = nr * inv_se * inv_se;       // |s|^2, s = col/se
            if (lane < 16) {
                float f = sqrtf(norm) / (1.0f + norm);
                float vnew = col * inv_se * f;       // v = s*sqrt(n)/(1+n)
                if (it == 0)      vbuf[lane]  = vnew;
                else if (it == 1) vbuf[lane] += vnew;  // cumulative V
                if (it == 2 && lane == 0) out[b * K + k] = norm / (1.0f + norm);
            }
        }
        __syncthreads();
    }
}

extern "C" void kernel_launch(void* const* d_in, const int* in_sizes, int n_in,
                              void* d_out, int out_size, void* d_ws, size_t ws_size,
                              hipStream_t stream) {
    const float* u = (const float*)d_in[0];   // [1024, 2336, 4]
    const float* W = (const float*)d_in[1];   // [2, 2336, 4, 16]
    float* out = (float*)d_out;               // [1024, 2]
    caps_routing_kernel<<<dim3(2048), dim3(THREADS), 0, stream>>>(u, W, out);
}

// Round 6
// 225.117 us; speedup vs baseline: 2.0535x; 1.6353x over previous
//
#include <hip/hip_runtime.h>
#include <hip/hip_fp16.h>
#include <math.h>

// Caps1D dynamic routing — LDS-resident u_ji (fp16), 2 batches per block.
//
// u: [B=1024, R=2336, M=4] fp32 ; W: [K=2, R=2336, M=4, P=16] fp32
// out[b,k] = norm/(1+norm) of final squashed routing sum.
//
// ROUNDS 1-5 LESSON (measured): persistent per-thread uji arrays ALWAYS
// spill (64-128 VGPR caps; 300-670 MB scratch traffic). So u_ji goes to
// LDS instead: fp16, 2336 rows x 16, 74.75 KB per (b,k). One block owns
// (b0,b1) x k — the W row is read ONCE and feeds both batches, halving
// the dominant W L2 traffic (2048x598KB -> 1024x598KB).
//
// Routing math: b_r(t) = dot(u_ji[r], Vcum(t)), Vcum = v0 (+ v1). Softmax
// computed WITHOUT max subtraction (shift-invariant; logits |d| <~ 25 so
// exp() is safe in fp32) -> exactly ONE LDS sweep per iteration:
//   per row: d = u_ji[r].Vcum ; e = exp(d) ; se += e ; s_p += e*u_ji[r,p]
//
// LDS read pattern: 2 lanes per row (8 halves = 16 B each) -> lane L reads
// byte 16L -> banks 4L%32: all 32 banks, conflict-free.

#define THREADS 512
#define NWAVE 8

__global__ __launch_bounds__(THREADS, 2)
void caps_routing_kernel(const float* __restrict__ u,
                         const float* __restrict__ W,
                         float* __restrict__ out)
{
    constexpr int K = 2, R = 2336;

    extern __shared__ char smem[];
    __half* uji0 = (__half*)smem;               // R*16 halves = 74752 B
    __half* uji1 = (__half*)(smem + R * 32);    // R*16 halves
    float*  red  = (float*)(smem + 2 * R * 32); // [NWAVE][17]
    float*  vbuf = red + NWAVE * 17;            // [16] cumulative v

    const int bi    = blockIdx.x;               // 1024 blocks
    // same-XCD pairing: (bpair,k=0) and (bpair,k=1) are 8 blocks apart
    const int k     = (bi >> 3) & 1;
    const int bpair = (bi & 7) | ((bi >> 4) << 3);
    const int b0    = bpair * 2, b1 = b0 + 1;

    const int tid  = threadIdx.x;
    const int lane = tid & 63;
    const int wave = tid >> 6;

    const float4* __restrict__ u4 = (const float4*)u;
    const float4* __restrict__ w4 = (const float4*)W;

    // ---- build u_ji for BOTH batches from ONE W read ----
    #pragma unroll
    for (int j = 0; j < 5; ++j) {
        const int r = tid + j * THREADS;
        if (r < R) {
            float4 uu0 = u4[b0 * R + r];
            float4 uu1 = u4[b1 * R + r];
            const float4* wp = w4 + (size_t)(k * R + r) * 16;
            float a0[16], a1[16];
            #pragma unroll
            for (int m = 0; m < 4; ++m) {
                const float um0 = (m == 0) ? uu0.x : (m == 1) ? uu0.y : (m == 2) ? uu0.z : uu0.w;
                const float um1 = (m == 0) ? uu1.x : (m == 1) ? uu1.y : (m == 2) ? uu1.z : uu1.w;
                #pragma unroll
                for (int q = 0; q < 4; ++q) {
                    float4 w = wp[m * 4 + q];
                    if (m == 0) {
                        a0[q*4+0] = um0*w.x; a0[q*4+1] = um0*w.y; a0[q*4+2] = um0*w.z; a0[q*4+3] = um0*w.w;
                        a1[q*4+0] = um1*w.x; a1[q*4+1] = um1*w.y; a1[q*4+2] = um1*w.z; a1[q*4+3] = um1*w.w;
                    } else {
                        a0[q*4+0] += um0*w.x; a0[q*4+1] += um0*w.y; a0[q*4+2] += um0*w.z; a0[q*4+3] += um0*w.w;
                        a1[q*4+0] += um1*w.x; a1[q*4+1] += um1*w.y; a1[q*4+2] += um1*w.z; a1[q*4+3] += um1*w.w;
                    }
                }
            }
            __half2* d0 = (__half2*)(uji0 + r * 16);
            __half2* d1 = (__half2*)(uji1 + r * 16);
            #pragma unroll
            for (int h = 0; h < 8; ++h) {
                d0[h] = __floats2half2_rn(a0[2*h], a0[2*h+1]);
                d1[h] = __floats2half2_rn(a1[2*h], a1[2*h+1]);
            }
        }
    }
    __syncthreads();

    // ---- routing: 2 units x 3 iterations, one LDS sweep per iteration ----
    #pragma unroll 1
    for (int unit = 0; unit < 2; ++unit) {
        const char* U  = (const char*)(unit ? uji1 : uji0);
        const int   bb = unit ? b1 : b0;

        #pragma unroll 1
        for (int it = 0; it < 3; ++it) {
            float vpart[8];
            if (it > 0) {
                #pragma unroll
                for (int i = 0; i < 8; ++i) vpart[i] = vbuf[(lane & 1) * 8 + i];
            }
            float s8[8] = {0,0,0,0,0,0,0,0};
            float se = 0.0f;

            // 2 lanes per row; wave covers 32 rows/step; block 256 rows/step
            #pragma unroll 2
            for (int step = 0; step < 10; ++step) {
                const int row = step * 256 + wave * 32 + (lane >> 1);
                const bool ok = (row < R);
                const int  rc = ok ? row : (R - 1);
                float4 raw = *(const float4*)(U + rc * 32 + (lane & 1) * 16);
                const __half2* hp = (const __half2*)&raw;
                float h[8];
                #pragma unroll
                for (int q = 0; q < 4; ++q) {
                    float2 f = __half22float2(hp[q]);
                    h[2*q] = f.x; h[2*q+1] = f.y;
                }
                float e;
                if (it == 0) {
                    e = 1.0f;
                } else {
                    float d = 0.0f;
                    #pragma unroll
                    for (int i = 0; i < 8; ++i) d += h[i] * vpart[i];
                    d += __shfl_xor(d, 1);      // combine the two half-dots
                    e = __expf(d);              // no max-subtract (see header)
                }
                e = ok ? e : 0.0f;
                se += e;
                #pragma unroll
                for (int i = 0; i < 8; ++i) s8[i] += e * h[i];
            }

            // reduce across row-pairs within the wave (parity-preserving xor)
            #pragma unroll
            for (int o = 2; o <= 32; o <<= 1) {
                se += __shfl_xor(se, o);
                #pragma unroll
                for (int i = 0; i < 8; ++i) s8[i] += __shfl_xor(s8[i], o);
            }
            if (lane < 2) {
                #pragma unroll
                for (int i = 0; i < 8; ++i) red[wave * 17 + (lane & 1) * 8 + i] = s8[i];
                if (lane == 0) red[wave * 17 + 16] = se;
            }
            __syncthreads();

            // wave 0, lanes 0..16: cross-wave column sums + squash
            if (wave == 0 && lane < 17) {
                float col = red[lane];
                #pragma unroll
                for (int w = 1; w < NWAVE; ++w) col += red[w * 17 + lane];
                float se_t = __shfl(col, 16);        // lane 16 holds sum(e)
                if (lane < 16) {
                    float nr = col * col;            // xor net stays in [0,16)
                    nr += __shfl_xor(nr, 1);
                    nr += __shfl_xor(nr, 2);
                    nr += __shfl_xor(nr, 4);
                    nr += __shfl_xor(nr, 8);
                    float inv  = 1.0f / se_t;
                    float norm = nr * inv * inv;     // |s|^2, s = col/se
                    float f    = sqrtf(norm) / (1.0f + norm);
                    float vnew = col * inv * f;      // v = s*sqrt(n)/(1+n)
                    if (it == 0)      vbuf[lane]  = vnew;
                    else if (it == 1) vbuf[lane] += vnew;   // cumulative V
                    if (it == 2 && lane == 0) out[bb * K + k] = norm / (1.0f + norm);
                }
            }
            __syncthreads();
        }
    }
}

extern "C" void kernel_launch(void* const* d_in, const int* in_sizes, int n_in,
                              void* d_out, int out_size, void* d_ws, size_t ws_size,
                              hipStream_t stream) {
    const float* u = (const float*)d_in[0];   // [1024, 2336, 4]
    const float* W = (const float*)d_in[1];   // [2, 2336, 4, 16]
    float* out = (float*)d_out;               // [1024, 2]
    constexpr int R = 2336;
    const size_t lds_bytes = 2 * R * 32 + (NWAVE * 17 + 16) * sizeof(float); // 150112
    caps_routing_kernel<<<dim3(1024), dim3(THREADS), lds_bytes, stream>>>(u, W, out);
}

// Round 7
// 216.906 us; speedup vs baseline: 2.1313x; 1.0379x over previous
//
#include <hip/hip_runtime.h>
#include <hip/hip_fp16.h>
#include <math.h>

// Caps1D dynamic routing — LDS-resident u_ji (fp16), ONE (b,k) per block.
//
// u: [B=1024, R=2336, M=4] fp32 ; W: [K=2, R=2336, M=4, P=16] fp32
// out[b,k] = norm/(1+norm) of final squashed routing sum.
//
// Round-6 lessons (measured):
//  * persistent per-thread uji always spills -> LDS-resident fp16 u_ji. GOOD
//    (WRITE_SIZE 299MB -> 16KB, dur 368 -> 172 steady).
//  * 2-batches-per-block (150KB LDS) killed occupancy (1 block/CU, 2 w/SIMD)
//    and serialized 6 sweeps; HBM was at 1.7% so the W-traffic saving it
//    bought was worthless -> now one (b,k) per block, 74.75KB, 2 blocks/CU.
//  * 8.37M LDS conflict cycles came from half2 (b32) build writes with 32B
//    row stride (64 lanes -> 4 banks, 16-way). Packed b128 writes fix it.
//
// Sweep layout: 2 lanes per row, lane L reads byte base+16L (conflict-free);
// all 10 steps' ds_read_b128 issued before use (latency hiding via ILP).
// Softmax without max-subtract (logits bounded, |v|<1, fp32 exp safe).

#define THREADS 512
#define NWAVE 8
#define RR 2336
#define KK 2

__global__ __launch_bounds__(THREADS, 2)
void caps_routing_kernel(const float* __restrict__ u,
                         const float* __restrict__ W,
                         float* __restrict__ out)
{
    extern __shared__ char smem[];
    __half* uji  = (__half*)smem;                    // RR*16 halves = 74752 B
    float*  red  = (float*)(smem + RR * 32);         // [NWAVE][17]
    float*  vbuf = red + NWAVE * 17;                 // [16] cumulative v

    const int bi   = blockIdx.x;                     // 2048 blocks
    const int b    = bi >> 1;
    const int k    = bi & 1;
    const int tid  = threadIdx.x;
    const int lane = tid & 63;
    const int wave = tid >> 6;

    const float4* __restrict__ u4 = (const float4*)u;
    const float4* __restrict__ w4 = (const float4*)W;

    // ---- build u_ji[r,:] = u[b,r,:] @ W[k,r,:,:]  (fp32 math, fp16 store) ----
    #pragma unroll
    for (int j = 0; j < 5; ++j) {
        const int r = tid + j * THREADS;
        if (r < RR) {
            float4 uu = u4[b * RR + r];
            const float4* wp = w4 + (size_t)(k * RR + r) * 16;
            float a[16];
            {
                float4 w0 = wp[0], w1 = wp[1], w2 = wp[2], w3 = wp[3];
                a[ 0] = uu.x * w0.x; a[ 1] = uu.x * w0.y; a[ 2] = uu.x * w0.z; a[ 3] = uu.x * w0.w;
                a[ 4] = uu.x * w1.x; a[ 5] = uu.x * w1.y; a[ 6] = uu.x * w1.z; a[ 7] = uu.x * w1.w;
                a[ 8] = uu.x * w2.x; a[ 9] = uu.x * w2.y; a[10] = uu.x * w2.z; a[11] = uu.x * w2.w;
                a[12] = uu.x * w3.x; a[13] = uu.x * w3.y; a[14] = uu.x * w3.z; a[15] = uu.x * w3.w;
            }
            #pragma unroll
            for (int m = 1; m < 4; ++m) {
                const float um = (m == 1) ? uu.y : (m == 2) ? uu.z : uu.w;
                float4 w0 = wp[4*m+0], w1 = wp[4*m+1], w2 = wp[4*m+2], w3 = wp[4*m+3];
                a[ 0] += um * w0.x; a[ 1] += um * w0.y; a[ 2] += um * w0.z; a[ 3] += um * w0.w;
                a[ 4] += um * w1.x; a[ 5] += um * w1.y; a[ 6] += um * w1.z; a[ 7] += um * w1.w;
                a[ 8] += um * w2.x; a[ 9] += um * w2.y; a[10] += um * w2.z; a[11] += um * w2.w;
                a[12] += um * w3.x; a[13] += um * w3.y; a[14] += um * w3.z; a[15] += um * w3.w;
            }
            // pack 16 halves into two float4s -> two ds_write_b128 (2-way max)
            union { float4 f4[2]; __half2 h2[8]; } pk;
            #pragma unroll
            for (int h = 0; h < 8; ++h) pk.h2[h] = __floats2half2_rn(a[2*h], a[2*h+1]);
            float4* dst = (float4*)(uji + r * 16);
            dst[0] = pk.f4[0];
            dst[1] = pk.f4[1];
        }
    }
    __syncthreads();

    // ---- 3 routing iterations, one LDS sweep each ----
    #pragma unroll 1
    for (int it = 0; it < 3; ++it) {
        float vpart[8];
        if (it > 0) {
            #pragma unroll
            for (int i = 0; i < 8; ++i) vpart[i] = vbuf[(lane & 1) * 8 + i];
        }

        // issue ALL 10 row-loads first (ILP over ~120cyc LDS latency)
        float4 raw[10];
        #pragma unroll
        for (int s = 0; s < 10; ++s) {
            int row = s * 256 + wave * 32 + (lane >> 1);
            row = (row < RR) ? row : (RR - 1);               // clamp; masked below
            raw[s] = *(const float4*)((const char*)uji + row * 32 + (lane & 1) * 16);
        }

        float s8[8] = {0,0,0,0,0,0,0,0};
        float se = 0.0f;
        #pragma unroll
        for (int s = 0; s < 10; ++s) {
            const bool ok = (s * 256 + wave * 32 + (lane >> 1)) < RR;
            const __half2* hp = (const __half2*)&raw[s];
            float h[8];
            #pragma unroll
            for (int q = 0; q < 4; ++q) {
                float2 f = __half22float2(hp[q]);
                h[2*q] = f.x; h[2*q+1] = f.y;
            }
            float e;
            if (it == 0) {
                e = ok ? 1.0f : 0.0f;                        // uniform softmax
            } else {
                float d = 0.0f;
                #pragma unroll
                for (int i = 0; i < 8; ++i) d += h[i] * vpart[i];
                d += __shfl_xor(d, 1);                       // join the two half-dots
                e = ok ? __expf(d) : 0.0f;                   // no max-subtract
            }
            se += e;
            #pragma unroll
            for (int i = 0; i < 8; ++i) s8[i] += e * h[i];
        }

        // parity-preserving xor reduction (offsets 2..32 keep lane bit0)
        #pragma unroll
        for (int o = 2; o <= 32; o <<= 1) {
            se += __shfl_xor(se, o);
            #pragma unroll
            for (int i = 0; i < 8; ++i) s8[i] += __shfl_xor(s8[i], o);
        }
        if (lane < 2) {
            #pragma unroll
            for (int i = 0; i < 8; ++i) red[wave * 17 + (lane & 1) * 8 + i] = s8[i];
            if (lane == 0) red[wave * 17 + 16] = se;
        }
        __syncthreads();

        // wave 0, lanes 0..16: cross-wave column sums + squash
        if (wave == 0 && lane < 17) {
            float col = red[lane];
            #pragma unroll
            for (int w = 1; w < NWAVE; ++w) col += red[w * 17 + lane];
            float se_t = __shfl(col, 16);                    // lane 16: sum(e)
            if (lane < 16) {
                float nr = col * col;                        // xor net in [0,16)
                nr += __shfl_xor(nr, 1);
                nr += __shfl_xor(nr, 2);
                nr += __shfl_xor(nr, 4);
                nr += __shfl_xor(nr, 8);
                float inv  = 1.0f / se_t;
                float norm = nr * inv * inv;                 // |s|^2, s = col/se
                float f    = sqrtf(norm) / (1.0f + norm);
                float vnew = col * inv * f;                  // v = s*sqrt(n)/(1+n)
                if (it == 0)      vbuf[lane]  = vnew;
                else if (it == 1) vbuf[lane] += vnew;        // cumulative V
                if (it == 2 && lane == 0) out[b * KK + k] = norm / (1.0f + norm);
            }
        }
        __syncthreads();
    }
}

extern "C" void kernel_launch(void* const* d_in, const int* in_sizes, int n_in,
                              void* d_out, int out_size, void* d_ws, size_t ws_size,
                              hipStream_t stream) {
    const float* u = (const float*)d_in[0];   // [1024, 2336, 4]
    const float* W = (const float*)d_in[1];   // [2, 2336, 4, 16]
    float* out = (float*)d_out;               // [1024, 2]
    const size_t lds_bytes = RR * 32 + (NWAVE * 17 + 16) * sizeof(float); // 75360
    caps_routing_kernel<<<dim3(2048), dim3(THREADS), lds_bytes, stream>>>(u, W, out);
}

// Round 8
// 161.664 us; speedup vs baseline: 2.8595x; 1.3417x over previous
//
#include <hip/hip_runtime.h>
#include <hip/hip_fp16.h>
#include <math.h>

// Caps1D dynamic routing — coalesced fp16 W, LDS-resident u_ji.
//
// u: [B=1024, R=2336, M=4] fp32 ; W: [K=2, R=2336, M=4, P=16] fp32
// out[b,k] = norm/(1+norm) of final squashed routing sum.
//
// ROUND-7 DIAGNOSIS (measured): build-phase W loads were thread-per-row ->
// 64 lanes stride 256 B -> 64 cache lines per load instr (4x minimum).
// 41.6K line-transactions/block x 8 blocks/CU = 333K cyc at ~1 line/cyc/CU
// = 85% of the 389K-cycle runtime. Fix: prepass transposes W to fp16
// [k][m][r][p] in d_ws; build assigns lane=(row-in-8, p2) so every W load
// is 8 rows x 32 B CONTIGUOUS (4 lines, minimal). Also folds routing
// iteration 0 (uniform softmax, se == R exactly) into the build pass.

#define THREADS 512
#define NWAVE 8
#define RR 2336
#define KK 2

// ---- prepass: W fp32 [k][r][m][p] -> fp16 [k][m][r][p2 half2] ----
__global__ __launch_bounds__(256)
void w_to_fp16_kernel(const float* __restrict__ W, __half2* __restrict__ Wh2)
{
    const int n2 = KK * 4 * RR * 8;              // 149504 half2
    for (int j2 = blockIdx.x * 256 + threadIdx.x; j2 < n2; j2 += gridDim.x * 256) {
        const int k   = j2 / (4 * RR * 8);
        int rem       = j2 - k * (4 * RR * 8);
        const int m   = rem / (RR * 8);
        rem          -= m * (RR * 8);
        const int r   = rem >> 3;
        const int p2  = rem & 7;
        const float2 f = *(const float2*)(W + (((size_t)(k * RR + r) * 4 + m) * 16 + p2 * 2));
        Wh2[j2] = __floats2half2_rn(f.x, f.y);
    }
}

__global__ __launch_bounds__(THREADS, 2)
void caps_routing_kernel(const float* __restrict__ u,
                         const __half2* __restrict__ Wh2,
                         float* __restrict__ out)
{
    extern __shared__ char smem[];
    __half* uji  = (__half*)smem;                    // RR*16 halves = 74752 B
    float*  red  = (float*)(smem + RR * 32);         // [NWAVE][17]
    float*  vbuf = red + NWAVE * 17;                 // [16] cumulative v

    const int bi   = blockIdx.x;                     // 2048 blocks
    const int b    = bi >> 1;
    const int k    = bi & 1;
    const int tid  = threadIdx.x;
    const int lane = tid & 63;
    const int wave = tid >> 6;
    const int p2   = lane & 7;                       // half2 column 0..7
    const int g    = lane >> 3;                      // row-in-group 0..7

    const float4* __restrict__ u4p = (const float4*)u;

    // ---- build u_ji (fp16 -> LDS) + iteration-0 accumulation (e == 1) ----
    // W fp16 layout: Wh2[((k*4+m)*RR + r)*8 + p2]; per-m load = 8 rows x 32 B
    // contiguous across the wave (4 cache lines, minimal).
    const __half2* __restrict__ wb = Wh2 + (size_t)(k * 4) * RR * 8 + p2;
    float sA = 0.0f, sB = 0.0f;
    #pragma unroll 2
    for (int i = 0; i < 37; ++i) {
        const int r0 = i * 64 + wave * 8 + g;
        const bool ok = r0 < RR;
        const int r  = ok ? r0 : RR - 1;             // clamp loads, mask effects
        float4 uu = u4p[b * RR + r];
        float2 w0 = __half22float2(wb[(size_t)(0 * RR + r) * 8]);
        float2 w1 = __half22float2(wb[(size_t)(1 * RR + r) * 8]);
        float2 w2 = __half22float2(wb[(size_t)(2 * RR + r) * 8]);
        float2 w3 = __half22float2(wb[(size_t)(3 * RR + r) * 8]);
        float ax = uu.x * w0.x + uu.y * w1.x + uu.z * w2.x + uu.w * w3.x;
        float ay = uu.x * w0.y + uu.y * w1.y + uu.z * w2.y + uu.w * w3.y;
        if (ok) {
            sA += ax; sB += ay;
            *(__half2*)(uji + r * 16 + p2 * 2) = __floats2half2_rn(ax, ay);
        }
    }
    // reduce iter-0 sums over g (xor 8/16/32 preserves p2)
    sA += __shfl_xor(sA, 8);  sB += __shfl_xor(sB, 8);
    sA += __shfl_xor(sA, 16); sB += __shfl_xor(sB, 16);
    sA += __shfl_xor(sA, 32); sB += __shfl_xor(sB, 32);
    if (lane < 8) {
        red[wave * 17 + 2 * p2]     = sA;
        red[wave * 17 + 2 * p2 + 1] = sB;
    }
    __syncthreads();

    // iteration-0 squash: se == R exactly (uniform softmax)
    if (wave == 0 && lane < 16) {
        float col = red[lane];
        #pragma unroll
        for (int w = 1; w < NWAVE; ++w) col += red[w * 17 + lane];
        float nr = col * col;
        nr += __shfl_xor(nr, 1);
        nr += __shfl_xor(nr, 2);
        nr += __shfl_xor(nr, 4);
        nr += __shfl_xor(nr, 8);
        const float inv  = 1.0f / (float)RR;
        const float norm = nr * inv * inv;
        const float f    = sqrtf(norm) / (1.0f + norm);
        vbuf[lane] = col * inv * f;                  // v0
    }
    __syncthreads();

    // ---- routing iterations 1,2: one LDS sweep each ----
    #pragma unroll 1
    for (int it = 1; it < 3; ++it) {
        float vpart[8];
        #pragma unroll
        for (int i = 0; i < 8; ++i) vpart[i] = vbuf[(lane & 1) * 8 + i];

        // issue all 10 row-loads up front (ILP over LDS latency)
        float4 raw[10];
        #pragma unroll
        for (int s = 0; s < 10; ++s) {
            int row = s * 256 + wave * 32 + (lane >> 1);
            row = (row < RR) ? row : (RR - 1);
            raw[s] = *(const float4*)((const char*)uji + row * 32 + (lane & 1) * 16);
        }

        float s8[8] = {0,0,0,0,0,0,0,0};
        float se = 0.0f;
        #pragma unroll
        for (int s = 0; s < 10; ++s) {
            const bool ok = (s * 256 + wave * 32 + (lane >> 1)) < RR;
            const __half2* hp = (const __half2*)&raw[s];
            float h[8];
            #pragma unroll
            for (int q = 0; q < 4; ++q) {
                float2 f = __half22float2(hp[q]);
                h[2*q] = f.x; h[2*q+1] = f.y;
            }
            float d = 0.0f;
            #pragma unroll
            for (int i = 0; i < 8; ++i) d += h[i] * vpart[i];
            d += __shfl_xor(d, 1);                   // join the two half-dots
            float e = ok ? __expf(d) : 0.0f;         // no max-subtract (bounded)
            se += e;
            #pragma unroll
            for (int i = 0; i < 8; ++i) s8[i] += e * h[i];
        }

        // parity-preserving xor reduction (offsets 2..32 keep lane bit0)
        #pragma unroll
        for (int o = 2; o <= 32; o <<= 1) {
            se += __shfl_xor(se, o);
            #pragma unroll
            for (int i = 0; i < 8; ++i) s8[i] += __shfl_xor(s8[i], o);
        }
        if (lane < 2) {
            #pragma unroll
            for (int i = 0; i < 8; ++i) red[wave * 17 + (lane & 1) * 8 + i] = s8[i];
            if (lane == 0) red[wave * 17 + 16] = se;
        }
        __syncthreads();

        if (wave == 0 && lane < 17) {
            float col = red[lane];
            #pragma unroll
            for (int w = 1; w < NWAVE; ++w) col += red[w * 17 + lane];
            float se_t = __shfl(col, 16);
            if (lane < 16) {
                float nr = col * col;
                nr += __shfl_xor(nr, 1);
                nr += __shfl_xor(nr, 2);
                nr += __shfl_xor(nr, 4);
                nr += __shfl_xor(nr, 8);
                float inv  = 1.0f / se_t;
                float norm = nr * inv * inv;
                float f    = sqrtf(norm) / (1.0f + norm);
                float vnew = col * inv * f;
                if (it == 1) vbuf[lane] += vnew;     // cumulative V
                else if (lane == 0) out[b * KK + k] = norm / (1.0f + norm);
            }
        }
        __syncthreads();
    }
}

extern "C" void kernel_launch(void* const* d_in, const int* in_sizes, int n_in,
                              void* d_out, int out_size, void* d_ws, size_t ws_size,
                              hipStream_t stream) {
    const float* u = (const float*)d_in[0];   // [1024, 2336, 4]
    const float* W = (const float*)d_in[1];   // [2, 2336, 4, 16]
    float* out = (float*)d_out;               // [1024, 2]
    __half2* Wh2 = (__half2*)d_ws;            // 299008 B of scratch

    w_to_fp16_kernel<<<dim3(256), dim3(256), 0, stream>>>(W, Wh2);

    const size_t lds_bytes = RR * 32 + (NWAVE * 17 + 16) * sizeof(float); // 75360
    caps_routing_kernel<<<dim3(2048), dim3(THREADS), lds_bytes, stream>>>(u, Wh2, out);
}